// Round 4
// baseline (299.999 us; speedup 1.0000x reference)
//
#include <hip/hip_runtime.h>

// Q6ArithmeticLayer: out = softmax(-hs * 3*(1 - dot(normalize(tanh(x@W^T)), normalize(P))))
// x: (32768, 1024) fp32 -> 134 MB stream (roofline ~20 us @ 6.8 TB/s measured fill BW).
// R6: fix R5's catastrophic spill. R5 counters: VGPR=64, WRITE 203 MB (scratch!),
//   FETCH 271 MB (134 ideal), kernel 162 us. The (256,4) cap + xv[2][8]=64-reg
//   load buffer forced the compiler to spill the whole buffer to scratch.
//   - x loads split into two j-batches of 8 x dwordx4 (xa[2][4], xb[2][4]):
//     peak live ~= 32(+32 if batch B hoists)+acc 12+wk 24+addr ~15 <= ~115,
//     fits the 128-VGPR step (4 waves/SIMD) WITH headroom -> no spill.
//   - all else unchanged from the refcheck-passing R5: half-wave decomposition
//     (each 32-lane half owns 2 tokens, lane covers 32 cols/token), W in LDS
//     (24 KB), xor16 scatter + xor{8,4,2,1} butterfly = 30 shfl / 4 tokens.
//   - blocks=1024 = exactly 4 resident blocks/CU (16 waves/CU), 2 iters/wave.
// Predicted: VGPR ~100-116, WRITE -> ~1 MB, FETCH -> ~137 MB, kernel ~25 us.

#define DIM 1024
#define NK 6
#define NPROTO 8
#define TPI 4  // tokens per wave iteration (2 per 32-lane half)

__global__ __launch_bounds__(256, 4) void q6_fused_kernel(
    const float* __restrict__ x,
    const float* __restrict__ W,
    const float* __restrict__ protos,
    const float* __restrict__ hs_ptr,
    float* __restrict__ out,
    int n_tokens, int n_waves)
{
    const int tid  = threadIdx.x;
    const int lane = tid & 63;
    const int wave_id = blockIdx.x * (blockDim.x >> 6) + (tid >> 6);
    const int h   = lane >> 5;    // which half: owns tokens {2h, 2h+1}
    const int sub = lane & 31;    // sub-lane within half (32 cols/token each)

    // --- stage W into LDS once per block: 6 x 1024 fp32 = 24 KB, straight copy ---
    __shared__ float4 wlds[NK * (DIM / 4)];   // wlds[k*256 + c] = W[k][4c..4c+3]
#pragma unroll
    for (int i = 0; i < (NK * DIM / 4) / 256; ++i)   // 6 iterations
        wlds[i * 256 + tid] = reinterpret_cast<const float4*>(W)[i * 256 + tid];

    // --- normalized prototype for this lane's proto slot (while W stage in flight) ---
    const int pl = lane & 7;
    float p[NK];
#pragma unroll
    for (int k = 0; k < NK; ++k) p[k] = protos[pl * NK + k];
    {
        float pn = sqrtf(p[0]*p[0] + p[1]*p[1] + p[2]*p[2] + p[3]*p[3] + p[4]*p[4] + p[5]*p[5]);
        float inv = 1.0f / fmaxf(pn, 1e-12f);
#pragma unroll
        for (int k = 0; k < NK; ++k) p[k] *= inv;
    }
    const float hs = hs_ptr[0];

    __syncthreads();

    const bool hi4 = (lane & 16) != 0;
    const int tloc = lane >> 4;   // 16-lane group g ends up owning token tb+g
    const int pidx = lane & 15;   // proto slot within the group (active if <8)

    for (int tb = wave_id * TPI; tb < n_tokens; tb += n_waves * TPI) {
        // lane covers cols [sub*4 + j*128 .. +3], j = 0..7, rows tb+2h, tb+2h+1
        const float* xt = x + (size_t)(tb + 2 * h) * DIM + sub * 4;

        float acc[2][NK];
#pragma unroll
        for (int t = 0; t < 2; ++t)
#pragma unroll
            for (int k = 0; k < NK; ++k) acc[t][k] = 0.0f;

        // ---- batch A: j = 0..3 (cols 0..511), 8 x global_load_dwordx4 ----
        float4 xa[2][4];
#pragma unroll
        for (int j = 0; j < 4; ++j) {
            xa[0][j] = *reinterpret_cast<const float4*>(&xt[j * 128]);
            xa[1][j] = *reinterpret_cast<const float4*>(&xt[DIM + j * 128]);
        }
        // ---- batch B: j = 4..7 (cols 512..1023) — compiler hoists if regs allow ----
        float4 xb[2][4];
#pragma unroll
        for (int j = 0; j < 4; ++j) {
            xb[0][j] = *reinterpret_cast<const float4*>(&xt[(j + 4) * 128]);
            xb[1][j] = *reinterpret_cast<const float4*>(&xt[DIM + (j + 4) * 128]);
        }

        // ---- compute batch A ----
#pragma unroll
        for (int j = 0; j < 4; ++j) {
            float4 wk[NK];
#pragma unroll
            for (int k = 0; k < NK; ++k)
                wk[k] = wlds[k * 256 + j * 32 + sub];   // 2-way broadcast across halves
#pragma unroll
            for (int t = 0; t < 2; ++t) {
                const float4 xvj = xa[t][j];
#pragma unroll
                for (int k = 0; k < NK; ++k) {
                    float a = acc[t][k];
                    a = fmaf(xvj.x, wk[k].x, a);
                    a = fmaf(xvj.y, wk[k].y, a);
                    a = fmaf(xvj.z, wk[k].z, a);
                    a = fmaf(xvj.w, wk[k].w, a);
                    acc[t][k] = a;
                }
            }
        }
        // ---- compute batch B ----
#pragma unroll
        for (int j = 0; j < 4; ++j) {
            float4 wk[NK];
#pragma unroll
            for (int k = 0; k < NK; ++k)
                wk[k] = wlds[k * 256 + (j + 4) * 32 + sub];
#pragma unroll
            for (int t = 0; t < 2; ++t) {
                const float4 xvj = xb[t][j];
#pragma unroll
                for (int k = 0; k < NK; ++k) {
                    float a = acc[t][k];
                    a = fmaf(xvj.x, wk[k].x, a);
                    a = fmaf(xvj.y, wk[k].y, a);
                    a = fmaf(xvj.z, wk[k].z, a);
                    a = fmaf(xvj.w, wk[k].w, a);
                    acc[t][k] = a;
                }
            }
        }

        // ---- step 1: xor16 — token reduce-scatter within each half (6 shfl) ----
        // after: 16-lane group g = lane>>4 owns token tb+g (g = 2h + (bit4))
        float z[NK];
#pragma unroll
        for (int k = 0; k < NK; ++k) {
            float send = hi4 ? acc[0][k] : acc[1][k];
            float keep = hi4 ? acc[1][k] : acc[0][k];
            z[k] = keep + __shfl_xor(send, 16, 64);
        }

        // ---- steps 2-5: butterfly within the 16-lane group (24 shfl) ----
#pragma unroll
        for (int off = 8; off >= 1; off >>= 1)
#pragma unroll
            for (int k = 0; k < NK; ++k)
                z[k] += __shfl_xor(z[k], off, 64);

        // ---- epilogue: lanes p<8 of each group handle proto p of token tloc ----
        if (pidx < NPROTO) {
            float zz[NK];
            float nrm2 = 0.0f;
#pragma unroll
            for (int k = 0; k < NK; ++k) {
                float a = z[k];
                // tanh(a) = sign(a) * (1-e)/(1+e), e = exp(-2|a|) — hw v_exp_f32
                float e = __expf(-2.0f * fabsf(a));
                float th = (1.0f - e) / (1.0f + e);
                zz[k] = copysignf(th, a);
                nrm2 = fmaf(zz[k], zz[k], nrm2);
            }
            float inv = 1.0f / fmaxf(sqrtf(nrm2), 1e-6f);
            float dot = (zz[0]*p[0] + zz[1]*p[1] + zz[2]*p[2] +
                         zz[3]*p[3] + zz[4]*p[4] + zz[5]*p[5]) * inv;
            float logit = -hs * (6.0f - dot * 6.0f) * 0.5f;
            // softmax over the 8 proto lanes (xor 1,2,4 stays in the subgroup)
            float m = logit;
            m = fmaxf(m, __shfl_xor(m, 1, 64));
            m = fmaxf(m, __shfl_xor(m, 2, 64));
            m = fmaxf(m, __shfl_xor(m, 4, 64));
            float e = __expf(logit - m);
            float s = e;
            s += __shfl_xor(s, 1, 64);
            s += __shfl_xor(s, 2, 64);
            s += __shfl_xor(s, 4, 64);
            out[(size_t)(tb + tloc) * NPROTO + pidx] = e / s;
        }
    }
}

extern "C" void kernel_launch(void* const* d_in, const int* in_sizes, int n_in,
                              void* d_out, int out_size, void* d_ws, size_t ws_size,
                              hipStream_t stream) {
    const float* x      = (const float*)d_in[0];
    const float* W      = (const float*)d_in[1];
    const float* protos = (const float*)d_in[2];
    const float* hs     = (const float*)d_in[3];
    float* out = (float*)d_out;

    const int n_tokens = in_sizes[0] / DIM;   // 32768
    const int blocks = 1024;                  // 4 blocks/CU resident, 2 iters/wave
    const int threads = 256;
    const int n_waves = blocks * (threads / 64);

    q6_fused_kernel<<<blocks, threads, 0, stream>>>(
        x, W, protos, hs, out, n_tokens, n_waves);
}

// Round 6
// 258.862 us; speedup vs baseline: 1.1589x; 1.1589x over previous
//
#include <hip/hip_runtime.h>

// Q6ArithmeticLayer: out = softmax(-hs * 3*(1 - dot(normalize(tanh(x@W^T)), normalize(P))))
// x: (32768, 1024) fp32 -> 134 MB stream (roofline ~20 us @ 6.8 TB/s measured fill BW).
// R8 == R7 resubmit (container failure; R7 never executed).
// R7: revert launch bound (256,4) -> (256,3). R5/R6 counters proved (256,4)
//   clamps the allocator to 64 VGPR on this compiler (VGPR_Count=64 both
//   rounds, ~203 MB scratch WRITE, 271 MB FETCH, kernel 164 us). (256,3) was
//   spill-free in R3 (~170-VGPR budget). Body unchanged from R6: nominal live
//   set ~90-120 regs -> allocator should land ~110-140 -> floor(512/V) = 3-4
//   blocks/CU (12-16 waves/CU) with LDS at 24 KB (6 blocks/CU, not binding).
//   - half-wave decomposition: each 32-lane half owns 2 tokens; lane covers 32
//     cols/token; acc[2][6]=12 VGPR; two 8-load batches (xa/xb [2][4]).
//   - W in LDS (24 KB), re-read per j-chunk as ds_read_b128 (broadcast, no
//     bank conflicts: SQ_LDS_BANK_CONFLICT=0 measured).
//   - reduction: xor16 token reduce-scatter (6 shfl) + xor{8,4,2,1} butterfly
//     (24 shfl) = 30 shfl / 4 tokens, 5 serial stages.
//   - blocks=1024, 2 iters/wave.
// Predicted: VGPR 100-144 (64 again = cap theory wrong), WRITE ~1 MB,
//   FETCH ~137 MB, kernel 20-35 us, dur ~185-195.

#define DIM 1024
#define NK 6
#define NPROTO 8
#define TPI 4  // tokens per wave iteration (2 per 32-lane half)

__global__ __launch_bounds__(256, 3) void q6_fused_kernel(
    const float* __restrict__ x,
    const float* __restrict__ W,
    const float* __restrict__ protos,
    const float* __restrict__ hs_ptr,
    float* __restrict__ out,
    int n_tokens, int n_waves)
{
    const int tid  = threadIdx.x;
    const int lane = tid & 63;
    const int wave_id = blockIdx.x * (blockDim.x >> 6) + (tid >> 6);
    const int h   = lane >> 5;    // which half: owns tokens {2h, 2h+1}
    const int sub = lane & 31;    // sub-lane within half (32 cols/token each)

    // --- stage W into LDS once per block: 6 x 1024 fp32 = 24 KB, straight copy ---
    __shared__ float4 wlds[NK * (DIM / 4)];   // wlds[k*256 + c] = W[k][4c..4c+3]
#pragma unroll
    for (int i = 0; i < (NK * DIM / 4) / 256; ++i)   // 6 iterations
        wlds[i * 256 + tid] = reinterpret_cast<const float4*>(W)[i * 256 + tid];

    // --- normalized prototype for this lane's proto slot (while W stage in flight) ---
    const int pl = lane & 7;
    float p[NK];
#pragma unroll
    for (int k = 0; k < NK; ++k) p[k] = protos[pl * NK + k];
    {
        float pn = sqrtf(p[0]*p[0] + p[1]*p[1] + p[2]*p[2] + p[3]*p[3] + p[4]*p[4] + p[5]*p[5]);
        float inv = 1.0f / fmaxf(pn, 1e-12f);
#pragma unroll
        for (int k = 0; k < NK; ++k) p[k] *= inv;
    }
    const float hs = hs_ptr[0];

    __syncthreads();

    const bool hi4 = (lane & 16) != 0;
    const int tloc = lane >> 4;   // 16-lane group g ends up owning token tb+g
    const int pidx = lane & 15;   // proto slot within the group (active if <8)

    for (int tb = wave_id * TPI; tb < n_tokens; tb += n_waves * TPI) {
        // lane covers cols [sub*4 + j*128 .. +3], j = 0..7, rows tb+2h, tb+2h+1
        const float* xt = x + (size_t)(tb + 2 * h) * DIM + sub * 4;

        float acc[2][NK];
#pragma unroll
        for (int t = 0; t < 2; ++t)
#pragma unroll
            for (int k = 0; k < NK; ++k) acc[t][k] = 0.0f;

        // ---- batch A: j = 0..3 (cols 0..511), 8 x global_load_dwordx4 ----
        float4 xa[2][4];
#pragma unroll
        for (int j = 0; j < 4; ++j) {
            xa[0][j] = *reinterpret_cast<const float4*>(&xt[j * 128]);
            xa[1][j] = *reinterpret_cast<const float4*>(&xt[DIM + j * 128]);
        }
        // ---- batch B: j = 4..7 (cols 512..1023) — compiler hoists if regs allow ----
        float4 xb[2][4];
#pragma unroll
        for (int j = 0; j < 4; ++j) {
            xb[0][j] = *reinterpret_cast<const float4*>(&xt[(j + 4) * 128]);
            xb[1][j] = *reinterpret_cast<const float4*>(&xt[DIM + (j + 4) * 128]);
        }

        // ---- compute batch A ----
#pragma unroll
        for (int j = 0; j < 4; ++j) {
            float4 wk[NK];
#pragma unroll
            for (int k = 0; k < NK; ++k)
                wk[k] = wlds[k * 256 + j * 32 + sub];   // 2-way broadcast across halves
#pragma unroll
            for (int t = 0; t < 2; ++t) {
                const float4 xvj = xa[t][j];
#pragma unroll
                for (int k = 0; k < NK; ++k) {
                    float a = acc[t][k];
                    a = fmaf(xvj.x, wk[k].x, a);
                    a = fmaf(xvj.y, wk[k].y, a);
                    a = fmaf(xvj.z, wk[k].z, a);
                    a = fmaf(xvj.w, wk[k].w, a);
                    acc[t][k] = a;
                }
            }
        }
        // ---- compute batch B ----
#pragma unroll
        for (int j = 0; j < 4; ++j) {
            float4 wk[NK];
#pragma unroll
            for (int k = 0; k < NK; ++k)
                wk[k] = wlds[k * 256 + (j + 4) * 32 + sub];
#pragma unroll
            for (int t = 0; t < 2; ++t) {
                const float4 xvj = xb[t][j];
#pragma unroll
                for (int k = 0; k < NK; ++k) {
                    float a = acc[t][k];
                    a = fmaf(xvj.x, wk[k].x, a);
                    a = fmaf(xvj.y, wk[k].y, a);
                    a = fmaf(xvj.z, wk[k].z, a);
                    a = fmaf(xvj.w, wk[k].w, a);
                    acc[t][k] = a;
                }
            }
        }

        // ---- step 1: xor16 — token reduce-scatter within each half (6 shfl) ----
        // after: 16-lane group g = lane>>4 owns token tb+g (g = 2h + (bit4))
        float z[NK];
#pragma unroll
        for (int k = 0; k < NK; ++k) {
            float send = hi4 ? acc[0][k] : acc[1][k];
            float keep = hi4 ? acc[1][k] : acc[0][k];
            z[k] = keep + __shfl_xor(send, 16, 64);
        }

        // ---- steps 2-5: butterfly within the 16-lane group (24 shfl) ----
#pragma unroll
        for (int off = 8; off >= 1; off >>= 1)
#pragma unroll
            for (int k = 0; k < NK; ++k)
                z[k] += __shfl_xor(z[k], off, 64);

        // ---- epilogue: lanes p<8 of each group handle proto p of token tloc ----
        if (pidx < NPROTO) {
            float zz[NK];
            float nrm2 = 0.0f;
#pragma unroll
            for (int k = 0; k < NK; ++k) {
                float a = z[k];
                // tanh(a) = sign(a) * (1-e)/(1+e), e = exp(-2|a|) — hw v_exp_f32
                float e = __expf(-2.0f * fabsf(a));
                float th = (1.0f - e) / (1.0f + e);
                zz[k] = copysignf(th, a);
                nrm2 = fmaf(zz[k], zz[k], nrm2);
            }
            float inv = 1.0f / fmaxf(sqrtf(nrm2), 1e-6f);
            float dot = (zz[0]*p[0] + zz[1]*p[1] + zz[2]*p[2] +
                         zz[3]*p[3] + zz[4]*p[4] + zz[5]*p[5]) * inv;
            float logit = -hs * (6.0f - dot * 6.0f) * 0.5f;
            // softmax over the 8 proto lanes (xor 1,2,4 stays in the subgroup)
            float m = logit;
            m = fmaxf(m, __shfl_xor(m, 1, 64));
            m = fmaxf(m, __shfl_xor(m, 2, 64));
            m = fmaxf(m, __shfl_xor(m, 4, 64));
            float e = __expf(logit - m);
            float s = e;
            s += __shfl_xor(s, 1, 64);
            s += __shfl_xor(s, 2, 64);
            s += __shfl_xor(s, 4, 64);
            out[(size_t)(tb + tloc) * NPROTO + pidx] = e / s;
        }
    }
}

extern "C" void kernel_launch(void* const* d_in, const int* in_sizes, int n_in,
                              void* d_out, int out_size, void* d_ws, size_t ws_size,
                              hipStream_t stream) {
    const float* x      = (const float*)d_in[0];
    const float* W      = (const float*)d_in[1];
    const float* protos = (const float*)d_in[2];
    const float* hs     = (const float*)d_in[3];
    float* out = (float*)d_out;

    const int n_tokens = in_sizes[0] / DIM;   // 32768
    const int blocks = 1024;                  // 2 iters/wave
    const int threads = 256;
    const int n_waves = blocks * (threads / 64);

    q6_fused_kernel<<<blocks, threads, 0, stream>>>(
        x, W, protos, hs, out, n_tokens, n_waves);
}

// Round 9
// 207.870 us; speedup vs baseline: 1.4432x; 1.2453x over previous
//
#include <hip/hip_runtime.h>

// Q6ArithmeticLayer: out = softmax(-hs * 3*(1 - dot(normalize(tanh(x@W^T)), normalize(P))))
// x: (32768, 1024) fp32 -> 134 MB stream (roofline ~21 us @ 6.3-6.8 TB/s).
// R11 == R10 resubmit (broker timeout; R10 never executed).
// R10: R9's copy-kernel shape with the coverage bug fixed. R9 failed refcheck
//   (absmax 7.3e-2): 64 lanes x float4 = 256 floats, NOT 1024 -- it dotted only
//   the first quarter of each row. Correct coverage: 16 floats/lane = 4 x
//   dwordx4 at stride 256 (lane covers cols {j*256 + 4*lane}, the proven
//   R2/R3 layout). W at that coverage = 96 VGPR, so W returns to LDS (24 KB,
//   measured SQ_LDS_BANK_CONFLICT=0).
//   - per token/wave-iter: 4 global loads (+4 prefetch), 24 ds_read_b128,
//     96 FMAs, full 64-lane butterfly (36 shfl), 8-lane epilogue.
//   - NO __launch_bounds__: every cap this session ((256,4)->64 VGPR,
//     (256,3)->84) caused a 126-203 MB scratch round-trip. Nominal live set
//     ~80-95 VGPR -> ~5-6 waves/SIMD naturally; LDS caps 6 blocks/CU (24
//     waves/CU) -- far above the ~9 KB/CU in-flight needed for 6.3 TB/s.
//   - VALU: ~210 inst/token -> ~5.6 us total vs 21 us memory floor (4x slack).
//   - 2048 blocks x 256 thr = 8192 waves, 4 tokens/wave grid-stride.
// Predicted: passes (absmax ~5e-4); VGPR 80-100 no spill, WRITE ~1 MB,
//   FETCH ~137 MB, kernel 21-28 us, dur ~180-190.

#define DIM 1024
#define NK 6
#define NPROTO 8

__global__ void q6_fused_kernel(
    const float* __restrict__ x,
    const float* __restrict__ W,
    const float* __restrict__ protos,
    const float* __restrict__ hs_ptr,
    float* __restrict__ out,
    int n_tokens, int n_waves)
{
    const int tid  = threadIdx.x;
    const int lane = tid & 63;
    const int wave_id = blockIdx.x * (blockDim.x >> 6) + (tid >> 6);

    // --- stage W into LDS once per block: 6 x 1024 fp32 = 24 KB, straight copy ---
    __shared__ float4 wlds[NK * (DIM / 4)];   // wlds[k*256 + c] = W[k][4c..4c+3]
#pragma unroll
    for (int i = 0; i < (NK * DIM / 4) / 256; ++i)   // 6 iterations
        wlds[i * 256 + tid] = reinterpret_cast<const float4*>(W)[i * 256 + tid];

    // --- normalized prototype for this lane's proto slot (while W stage in flight) ---
    const int pl = lane & 7;
    float p[NK];
#pragma unroll
    for (int k = 0; k < NK; ++k) p[k] = protos[pl * NK + k];
    {
        float pn = sqrtf(p[0]*p[0] + p[1]*p[1] + p[2]*p[2] + p[3]*p[3] + p[4]*p[4] + p[5]*p[5]);
        float inv = 1.0f / fmaxf(pn, 1e-12f);
#pragma unroll
        for (int k = 0; k < NK; ++k) p[k] *= inv;
    }
    const float hs = hs_ptr[0];

    __syncthreads();

    // --- grid-stride over tokens, one token per wave-iteration, prefetch next ---
    int t = wave_id;
    if (t >= n_tokens) return;

    // lane covers cols {j*256 + 4*lane : j=0..3} -> 16 floats; 64 lanes = 1024
    float4 v[4];
#pragma unroll
    for (int j = 0; j < 4; ++j)
        v[j] = *reinterpret_cast<const float4*>(&x[(size_t)t * DIM + j * 256 + lane * 4]);

    for (; t < n_tokens; t += n_waves) {
        // prefetch next token (clamped; result unused on last iteration)
        int t2 = t + n_waves;
        int t2s = (t2 < n_tokens) ? t2 : t;
        float4 vn[4];
#pragma unroll
        for (int j = 0; j < 4; ++j)
            vn[j] = *reinterpret_cast<const float4*>(&x[(size_t)t2s * DIM + j * 256 + lane * 4]);

        // ---- 96 FMAs: partial dot over this lane's 16 cols ----
        float z[NK];
#pragma unroll
        for (int k = 0; k < NK; ++k) z[k] = 0.0f;
#pragma unroll
        for (int j = 0; j < 4; ++j) {
            float4 wk[NK];
#pragma unroll
            for (int k = 0; k < NK; ++k)
                wk[k] = wlds[k * 256 + j * 64 + lane];   // conflict-free b128
#pragma unroll
            for (int k = 0; k < NK; ++k) {
                float a = z[k];
                a = fmaf(v[j].x, wk[k].x, a);
                a = fmaf(v[j].y, wk[k].y, a);
                a = fmaf(v[j].z, wk[k].z, a);
                a = fmaf(v[j].w, wk[k].w, a);
                z[k] = a;
            }
        }

        // ---- full 64-lane butterfly: every lane gets all 6 sums (36 shfl) ----
#pragma unroll
        for (int off = 32; off >= 1; off >>= 1)
#pragma unroll
            for (int k = 0; k < NK; ++k)
                z[k] += __shfl_xor(z[k], off, 64);

        // ---- epilogue: lanes 0..7 handle proto lane of this token ----
        if (lane < NPROTO) {
            float zz[NK];
            float nrm2 = 0.0f;
#pragma unroll
            for (int k = 0; k < NK; ++k) {
                float a = z[k];
                // tanh(a) = sign(a) * (1-e)/(1+e), e = exp(-2|a|) — hw v_exp_f32
                float e = __expf(-2.0f * fabsf(a));
                float th = (1.0f - e) / (1.0f + e);
                zz[k] = copysignf(th, a);
                nrm2 = fmaf(zz[k], zz[k], nrm2);
            }
            float inv = 1.0f / fmaxf(sqrtf(nrm2), 1e-6f);
            float dot = (zz[0]*p[0] + zz[1]*p[1] + zz[2]*p[2] +
                         zz[3]*p[3] + zz[4]*p[4] + zz[5]*p[5]) * inv;
            float logit = -hs * (6.0f - dot * 6.0f) * 0.5f;
            // softmax over the 8 proto lanes (xor 1,2,4 stays within lanes 0..7)
            float m = logit;
            m = fmaxf(m, __shfl_xor(m, 1, 64));
            m = fmaxf(m, __shfl_xor(m, 2, 64));
            m = fmaxf(m, __shfl_xor(m, 4, 64));
            float e = __expf(logit - m);
            float s = e;
            s += __shfl_xor(s, 1, 64);
            s += __shfl_xor(s, 2, 64);
            s += __shfl_xor(s, 4, 64);
            out[(size_t)t * NPROTO + lane] = e / s;
        }

#pragma unroll
        for (int j = 0; j < 4; ++j) v[j] = vn[j];
    }
}

extern "C" void kernel_launch(void* const* d_in, const int* in_sizes, int n_in,
                              void* d_out, int out_size, void* d_ws, size_t ws_size,
                              hipStream_t stream) {
    const float* x      = (const float*)d_in[0];
    const float* W      = (const float*)d_in[1];
    const float* protos = (const float*)d_in[2];
    const float* hs     = (const float*)d_in[3];
    float* out = (float*)d_out;

    const int n_tokens = in_sizes[0] / DIM;   // 32768
    const int blocks = 2048;                  // 8192 waves, 4 tokens/wave
    const int threads = 256;
    const int n_waves = blocks * (threads / 64);

    q6_fused_kernel<<<blocks, threads, 0, stream>>>(
        x, W, protos, hs, out, n_tokens, n_waves);
}

// Round 10
// 197.973 us; speedup vs baseline: 1.5154x; 1.0500x over previous
//
#include <hip/hip_runtime.h>

// Q6ArithmeticLayer: out = softmax(-hs * 3*(1 - dot(normalize(tanh(x@W^T)), normalize(P))))
// x: (32768, 1024) fp32 -> 134 MB stream (roofline ~21 us @ 6.3-6.8 TB/s).
// R12: R8's refcheck-passing body + __launch_bounds__(256,2).
//   Allocator model (3 data points): budget ~= 256/N for launch_bounds(256,N):
//   N=4 -> 64 (R5/R6, 203 MB spill), N=3 -> 84 (R8, 129 MB spill), and NO
//   bounds ALSO caps at 64 (R11: VGPR=64, 45 MB spill, dur 207.9 -- worse than
//   R2's 192.1). N=2 (cap 128) is the only config never seen to spill (R2 ran
//   it all of last session). R8 body's live set ~100-110 fits 128 with margin.
//   HW occupancy quantizes at 64/128/256 -> VGPR in (64,128] = 4 waves/SIMD =
//   16 waves/CU: ~256 KB in flight/CU vs ~9 KB needed for 6.3 TB/s. Per-token
//   LDS cost (12 b128 + ~10 shfl ~= 200cy x 128 tok/CU ~= 11 us) is under the
//   21 us memory floor (a 1-token/wave variant would double it to ~31 us and
//   go LDS-bound -- rejected).
//   - half-wave decomposition: each 32-lane half owns 2 tokens; lane covers 32
//     cols/token; acc[2][6]=12 VGPR; two 8-load batches (xa/xb [2][4]).
//   - W in LDS (24 KB), ds_read_b128 broadcast (SQ_LDS_BANK_CONFLICT=0).
//   - reduction: xor16 scatter (6 shfl) + xor{8,4,2,1} butterfly (24) = 30/4tok.
//   - blocks=1024, 2 iters/wave.
// Predicted: VGPR 100-128 (64/84 falsifies cap model), WRITE ~1 MB,
//   FETCH ~137 MB, Occupancy 40-50%, kernel 22-32 us, dur ~160-185.

#define DIM 1024
#define NK 6
#define NPROTO 8
#define TPI 4  // tokens per wave iteration (2 per 32-lane half)

__global__ __launch_bounds__(256, 2) void q6_fused_kernel(
    const float* __restrict__ x,
    const float* __restrict__ W,
    const float* __restrict__ protos,
    const float* __restrict__ hs_ptr,
    float* __restrict__ out,
    int n_tokens, int n_waves)
{
    const int tid  = threadIdx.x;
    const int lane = tid & 63;
    const int wave_id = blockIdx.x * (blockDim.x >> 6) + (tid >> 6);
    const int h   = lane >> 5;    // which half: owns tokens {2h, 2h+1}
    const int sub = lane & 31;    // sub-lane within half (32 cols/token each)

    // --- stage W into LDS once per block: 6 x 1024 fp32 = 24 KB, straight copy ---
    __shared__ float4 wlds[NK * (DIM / 4)];   // wlds[k*256 + c] = W[k][4c..4c+3]
#pragma unroll
    for (int i = 0; i < (NK * DIM / 4) / 256; ++i)   // 6 iterations
        wlds[i * 256 + tid] = reinterpret_cast<const float4*>(W)[i * 256 + tid];

    // --- normalized prototype for this lane's proto slot (while W stage in flight) ---
    const int pl = lane & 7;
    float p[NK];
#pragma unroll
    for (int k = 0; k < NK; ++k) p[k] = protos[pl * NK + k];
    {
        float pn = sqrtf(p[0]*p[0] + p[1]*p[1] + p[2]*p[2] + p[3]*p[3] + p[4]*p[4] + p[5]*p[5]);
        float inv = 1.0f / fmaxf(pn, 1e-12f);
#pragma unroll
        for (int k = 0; k < NK; ++k) p[k] *= inv;
    }
    const float hs = hs_ptr[0];

    __syncthreads();

    const bool hi4 = (lane & 16) != 0;
    const int tloc = lane >> 4;   // 16-lane group g ends up owning token tb+g
    const int pidx = lane & 15;   // proto slot within the group (active if <8)

    for (int tb = wave_id * TPI; tb < n_tokens; tb += n_waves * TPI) {
        // lane covers cols [sub*4 + j*128 .. +3], j = 0..7, rows tb+2h, tb+2h+1
        const float* xt = x + (size_t)(tb + 2 * h) * DIM + sub * 4;

        float acc[2][NK];
#pragma unroll
        for (int t = 0; t < 2; ++t)
#pragma unroll
            for (int k = 0; k < NK; ++k) acc[t][k] = 0.0f;

        // ---- batch A: j = 0..3 (cols 0..511), 8 x global_load_dwordx4 ----
        float4 xa[2][4];
#pragma unroll
        for (int j = 0; j < 4; ++j) {
            xa[0][j] = *reinterpret_cast<const float4*>(&xt[j * 128]);
            xa[1][j] = *reinterpret_cast<const float4*>(&xt[DIM + j * 128]);
        }
        // ---- batch B: j = 4..7 (cols 512..1023) ----
        float4 xb[2][4];
#pragma unroll
        for (int j = 0; j < 4; ++j) {
            xb[0][j] = *reinterpret_cast<const float4*>(&xt[(j + 4) * 128]);
            xb[1][j] = *reinterpret_cast<const float4*>(&xt[DIM + (j + 4) * 128]);
        }

        // ---- compute batch A ----
#pragma unroll
        for (int j = 0; j < 4; ++j) {
            float4 wk[NK];
#pragma unroll
            for (int k = 0; k < NK; ++k)
                wk[k] = wlds[k * 256 + j * 32 + sub];   // 2-way broadcast across halves
#pragma unroll
            for (int t = 0; t < 2; ++t) {
                const float4 xvj = xa[t][j];
#pragma unroll
                for (int k = 0; k < NK; ++k) {
                    float a = acc[t][k];
                    a = fmaf(xvj.x, wk[k].x, a);
                    a = fmaf(xvj.y, wk[k].y, a);
                    a = fmaf(xvj.z, wk[k].z, a);
                    a = fmaf(xvj.w, wk[k].w, a);
                    acc[t][k] = a;
                }
            }
        }
        // ---- compute batch B ----
#pragma unroll
        for (int j = 0; j < 4; ++j) {
            float4 wk[NK];
#pragma unroll
            for (int k = 0; k < NK; ++k)
                wk[k] = wlds[k * 256 + (j + 4) * 32 + sub];
#pragma unroll
            for (int t = 0; t < 2; ++t) {
                const float4 xvj = xb[t][j];
#pragma unroll
                for (int k = 0; k < NK; ++k) {
                    float a = acc[t][k];
                    a = fmaf(xvj.x, wk[k].x, a);
                    a = fmaf(xvj.y, wk[k].y, a);
                    a = fmaf(xvj.z, wk[k].z, a);
                    a = fmaf(xvj.w, wk[k].w, a);
                    acc[t][k] = a;
                }
            }
        }

        // ---- step 1: xor16 — token reduce-scatter within each half (6 shfl) ----
        // after: 16-lane group g = lane>>4 owns token tb+g (g = 2h + (bit4))
        float z[NK];
#pragma unroll
        for (int k = 0; k < NK; ++k) {
            float send = hi4 ? acc[0][k] : acc[1][k];
            float keep = hi4 ? acc[1][k] : acc[0][k];
            z[k] = keep + __shfl_xor(send, 16, 64);
        }

        // ---- steps 2-5: butterfly within the 16-lane group (24 shfl) ----
#pragma unroll
        for (int off = 8; off >= 1; off >>= 1)
#pragma unroll
            for (int k = 0; k < NK; ++k)
                z[k] += __shfl_xor(z[k], off, 64);

        // ---- epilogue: lanes p<8 of each group handle proto p of token tloc ----
        if (pidx < NPROTO) {
            float zz[NK];
            float nrm2 = 0.0f;
#pragma unroll
            for (int k = 0; k < NK; ++k) {
                float a = z[k];
                // tanh(a) = sign(a) * (1-e)/(1+e), e = exp(-2|a|) — hw v_exp_f32
                float e = __expf(-2.0f * fabsf(a));
                float th = (1.0f - e) / (1.0f + e);
                zz[k] = copysignf(th, a);
                nrm2 = fmaf(zz[k], zz[k], nrm2);
            }
            float inv = 1.0f / fmaxf(sqrtf(nrm2), 1e-6f);
            float dot = (zz[0]*p[0] + zz[1]*p[1] + zz[2]*p[2] +
                         zz[3]*p[3] + zz[4]*p[4] + zz[5]*p[5]) * inv;
            float logit = -hs * (6.0f - dot * 6.0f) * 0.5f;
            // softmax over the 8 proto lanes (xor 1,2,4 stays in the subgroup)
            float m = logit;
            m = fmaxf(m, __shfl_xor(m, 1, 64));
            m = fmaxf(m, __shfl_xor(m, 2, 64));
            m = fmaxf(m, __shfl_xor(m, 4, 64));
            float e = __expf(logit - m);
            float s = e;
            s += __shfl_xor(s, 1, 64);
            s += __shfl_xor(s, 2, 64);
            s += __shfl_xor(s, 4, 64);
            out[(size_t)(tb + tloc) * NPROTO + pidx] = e / s;
        }
    }
}

extern "C" void kernel_launch(void* const* d_in, const int* in_sizes, int n_in,
                              void* d_out, int out_size, void* d_ws, size_t ws_size,
                              hipStream_t stream) {
    const float* x      = (const float*)d_in[0];
    const float* W      = (const float*)d_in[1];
    const float* protos = (const float*)d_in[2];
    const float* hs     = (const float*)d_in[3];
    float* out = (float*)d_out;

    const int n_tokens = in_sizes[0] / DIM;   // 32768
    const int blocks = 1024;                  // 4096 waves, 2 iters/wave
    const int threads = 256;
    const int n_waves = blocks * (threads / 64);

    q6_fused_kernel<<<blocks, threads, 0, stream>>>(
        x, W, protos, hs, out, n_tokens, n_waves);
}